// Round 7
// baseline (117.851 us; speedup 1.0000x reference)
//
#include <hip/hip_runtime.h>
#include <math.h>

// Problem: B=2, C=6 (DTI lower-tri), H=W=D=64. fp32 in, fp32 out.
// out[b,c,x,y,z] = (R^T M R)[I[c],J[c]]
//   M = 3x3 symmetric from trilinear-warped DTI (border clamp, align_corners)
//   R = orthogonal polar factor of J = I + du/dx  (== U @ Vh of SVD(J))
// 2-kernel pipeline:
//   1. warp_main: 2 voxels/thread (z-pair 2k,2k+1): f2u coalesced loads/stores,
//      z-derivs via lane shuffle, fp32 6-iter scaled-Newton polar. Voxels with
//      cond(J) > 1e4 get a NaN sentinel in output channel 0.
//   2. rescue: scans channel-0 plane (2 MB); NaN voxels re-solved in fp64
//      (14-iter normalized Newton) to match the float64 numpy reference.
#define NVOX 262144          // 64^3

typedef float f2u __attribute__((ext_vector_type(2), aligned(4)));

// trilinear warp of the 6 DTI channels at (xi,yi,zi) + (ux,uy,uz), border clamp
__device__ __forceinline__ void warp_m(const float* __restrict__ tb,
                                       int xi, int yi, int zi,
                                       float ux, float uy, float uz,
                                       float m[6])
{
    const float cx = fminf(fmaxf((float)xi + ux, 0.0f), 63.0f);
    const float cy = fminf(fmaxf((float)yi + uy, 0.0f), 63.0f);
    const float cz = fminf(fmaxf((float)zi + uz, 0.0f), 63.0f);
    const float fx0 = floorf(cx), fy0 = floorf(cy), fz0 = floorf(cz);
    const float fx = cx - fx0, fy = cy - fy0, fz = cz - fz0;
    const int x0 = (int)fx0, y0 = (int)fy0, z0 = (int)fz0;
    const int x1 = min(x0 + 1, 63), y1 = min(y0 + 1, 63);

    const float gx = 1.0f - fx, gy = 1.0f - fy, gz = 1.0f - fz;
    const float q00 = gx * gy, q01 = gx * fy, q10 = fx * gy, q11 = fx * fy;

    // z0/z1 adjacent -> one 8B load per (x,y) corner per channel.
    // z0==63 only when cz==63 (fz=0): shift base to 62, take .y for z0.
    const bool ztop = (z0 == 63);
    const int zb = ztop ? 62 : z0;
    const int p00 = (x0 * 64 + y0) * 64 + zb, p01 = (x0 * 64 + y1) * 64 + zb;
    const int p10 = (x1 * 64 + y0) * 64 + zb, p11 = (x1 * 64 + y1) * 64 + zb;

#pragma unroll
    for (int c = 0; c < 6; ++c) {
        const float* tc = tb + c * NVOX;
        const f2u v00 = *(const f2u*)(tc + p00);
        const f2u v01 = *(const f2u*)(tc + p01);
        const f2u v10 = *(const f2u*)(tc + p10);
        const f2u v11 = *(const f2u*)(tc + p11);
        const float l00 = (ztop ? v00.y : v00.x) * gz + v00.y * fz;
        const float l01 = (ztop ? v01.y : v01.x) * gz + v01.y * fz;
        const float l10 = (ztop ? v10.y : v10.x) * gz + v10.y * fz;
        const float l11 = (ztop ? v11.y : v11.x) * gz + v11.y * fz;
        m[c] = q00 * l00 + q01 * l01 + q10 * l10 + q11 * l11;
    }
}

// 6-iter fp32 scaled-Newton polar factor in place; returns Frobenius cond est.
__device__ __forceinline__ float polar3(float P[3][3])
{
    float cond_est = 0.0f;
#pragma unroll
    for (int it = 0; it < 6; ++it) {
        const float C00 = P[1][1] * P[2][2] - P[1][2] * P[2][1];
        const float C01 = P[1][2] * P[2][0] - P[1][0] * P[2][2];
        const float C02 = P[1][0] * P[2][1] - P[1][1] * P[2][0];
        const float C10 = P[0][2] * P[2][1] - P[0][1] * P[2][2];
        const float C11 = P[0][0] * P[2][2] - P[0][2] * P[2][0];
        const float C12 = P[0][1] * P[2][0] - P[0][0] * P[2][1];
        const float C20 = P[0][1] * P[1][2] - P[0][2] * P[1][1];
        const float C21 = P[0][2] * P[1][0] - P[0][0] * P[1][2];
        const float C22 = P[0][0] * P[1][1] - P[0][1] * P[1][0];
        const float det = P[0][0] * C00 + P[0][1] * C01 + P[0][2] * C02;

        const float n2 = P[0][0]*P[0][0] + P[0][1]*P[0][1] + P[0][2]*P[0][2]
                       + P[1][0]*P[1][0] + P[1][1]*P[1][1] + P[1][2]*P[1][2]
                       + P[2][0]*P[2][0] + P[2][1]*P[2][1] + P[2][2]*P[2][2];
        const float a2 = C00*C00 + C01*C01 + C02*C02
                       + C10*C10 + C11*C11 + C12*C12
                       + C20*C20 + C21*C21 + C22*C22;

        const float ad = fmaxf(fabsf(det), 1e-30f);
        if (it == 0) cond_est = sqrtf(n2 * a2) / ad;   // ~ ||X||_F ||X^-1||_F

        const float t  = fmaxf(sqrtf(a2 / n2), 1e-20f);
        const float sg = (det < 0.0f) ? -1.0f : 1.0f;
        const float c1 = 0.5f * sqrtf(t / ad);
        const float c2 = 0.5f * sg / sqrtf(t * ad);

        P[0][0] = c1 * P[0][0] + c2 * C00;  P[0][1] = c1 * P[0][1] + c2 * C01;  P[0][2] = c1 * P[0][2] + c2 * C02;
        P[1][0] = c1 * P[1][0] + c2 * C10;  P[1][1] = c1 * P[1][1] + c2 * C11;  P[1][2] = c1 * P[1][2] + c2 * C12;
        P[2][0] = c1 * P[2][0] + c2 * C20;  P[2][1] = c1 * P[2][1] + c2 * C21;  P[2][2] = c1 * P[2][2] + c2 * C22;
    }
    return cond_est;
}

// A6 = lower-tri of P^T * M * P
__device__ __forceinline__ void sandwich(const float P[3][3], const float m[6],
                                         float A6[6])
{
    const float M3[3][3] = {{m[0], m[1], m[3]},
                            {m[1], m[2], m[4]},
                            {m[3], m[4], m[5]}};
    float T[3][3];
#pragma unroll
    for (int i = 0; i < 3; ++i)
#pragma unroll
        for (int j = 0; j < 3; ++j)
            T[i][j] = P[0][i] * M3[0][j] + P[1][i] * M3[1][j] + P[2][i] * M3[2][j];
    A6[0] = T[0][0]*P[0][0] + T[0][1]*P[1][0] + T[0][2]*P[2][0];   // (0,0)
    A6[1] = T[1][0]*P[0][0] + T[1][1]*P[1][0] + T[1][2]*P[2][0];   // (1,0)
    A6[2] = T[1][0]*P[0][1] + T[1][1]*P[1][1] + T[1][2]*P[2][1];   // (1,1)
    A6[3] = T[2][0]*P[0][0] + T[2][1]*P[1][0] + T[2][2]*P[2][0];   // (2,0)
    A6[4] = T[2][0]*P[0][1] + T[2][1]*P[1][1] + T[2][2]*P[2][1];   // (2,1)
    A6[5] = T[2][0]*P[0][2] + T[2][1]*P[1][2] + T[2][2]*P[2][2];   // (2,2)
}

__global__ __launch_bounds__(256)
void warp_main(const float* __restrict__ dti,
               const float* __restrict__ ddf,
               float* __restrict__ out)
{
    const int idx2 = blockIdx.x * 256 + threadIdx.x;   // 262144 threads
    const int v0 = idx2 << 1;                // even voxel
    const int b  = v0 >> 18;
    const int r0 = v0 & (NVOX - 1);          // even; r1 = r0+1 same z-row
    const int x  = r0 >> 12;
    const int y  = (r0 >> 6) & 63;
    const int z0 = r0 & 63;                  // even, = 2*(lane&31)
    const int lane = threadIdx.x & 63;
    const int k = lane & 31;                 // z-pair index within row

    const float* db = ddf + (size_t)b * 3 * NVOX;

    // ---- center displacements for both voxels: f2u per channel ----
    f2u uc[3];
#pragma unroll
    for (int i = 0; i < 3; ++i) uc[i] = *(const f2u*)(db + i * NVOX + r0);

    // ---- Jacobian J = I + du/dx (np.gradient), both voxels ----
    const int xm = max(x - 1, 0), xp = min(x + 1, 63);
    const int ym = max(y - 1, 0), yp = min(y + 1, 63);
    const float sx = (xp - xm == 2) ? 0.5f : 1.0f;
    const float sy = (yp - ym == 2) ? 0.5f : 1.0f;
    const float sz0 = (k == 0) ? 1.0f : 0.5f;    // z=0: one-sided
    const float sz1 = (k == 31) ? 1.0f : 0.5f;   // z=63: one-sided

    float P0[3][3], P1[3][3];
#pragma unroll
    for (int i = 0; i < 3; ++i) {
        const float* ui = db + i * NVOX;
        const f2u vxp = *(const f2u*)(ui + (xp * 64 + y) * 64 + z0);
        const f2u vxm = *(const f2u*)(ui + (xm * 64 + y) * 64 + z0);
        const f2u vyp = *(const f2u*)(ui + (x * 64 + yp) * 64 + z0);
        const f2u vym = *(const f2u*)(ui + (x * 64 + ym) * 64 + z0);
        P0[i][0] = (vxp.x - vxm.x) * sx + (i == 0 ? 1.0f : 0.0f);
        P1[i][0] = (vxp.y - vxm.y) * sx + (i == 0 ? 1.0f : 0.0f);
        P0[i][1] = (vyp.x - vym.x) * sy + (i == 1 ? 1.0f : 0.0f);
        P1[i][1] = (vyp.y - vym.y) * sy + (i == 1 ? 1.0f : 0.0f);
        // z-derivs via shuffle of center values (z == 2*(lane&31) mapping)
        const float prev_y = __shfl(uc[i].y, (lane - 1) & 63);
        const float next_x = __shfl(uc[i].x, (lane + 1) & 63);
        const float zm0v = (k == 0)  ? uc[i].x : prev_y;   // u at z0-1 (clamped)
        const float zp1v = (k == 31) ? uc[i].y : next_x;   // u at z0+2 (clamped)
        P0[i][2] = (uc[i].y - zm0v) * sz0 + (i == 2 ? 1.0f : 0.0f);
        P1[i][2] = (zp1v - uc[i].x) * sz1 + (i == 2 ? 1.0f : 0.0f);
    }

    // ---- trilinear warp of DTI at both voxels ----
    const float* tb = dti + (size_t)b * 6 * NVOX;
    float m0[6], m1[6];
    warp_m(tb, x, y, z0,     uc[0].x, uc[1].x, uc[2].x, m0);
    warp_m(tb, x, y, z0 + 1, uc[0].y, uc[1].y, uc[2].y, m1);

    // ---- polar factors (two independent chains -> ILP) ----
    const float cond0 = polar3(P0);
    const float cond1 = polar3(P1);

    // ---- A = R^T M R, both voxels ----
    float A0[6], A1[6];
    sandwich(P0, m0, A0);
    sandwich(P1, m1, A1);

    // ---- NaN sentinel in channel 0 for ill-conditioned voxels ----
    const float qnan = __int_as_float(0x7fc00000);
    if (cond0 > 1e4f) A0[0] = qnan;
    if (cond1 > 1e4f) A1[0] = qnan;

    // ---- emit lower-tri (B,6,H,W,D): f2u stores (r0 even -> 8B aligned) ----
    float* ob = out + (size_t)b * 6 * NVOX + r0;
#pragma unroll
    for (int c = 0; c < 6; ++c) {
        f2u v; v.x = A0[c]; v.y = A1[c];
        *(f2u*)(ob + c * NVOX) = v;
    }
}

// Scan channel-0 plane for NaN sentinels; fp64 re-solve those voxels.
__global__ __launch_bounds__(256)
void rescue(const float* __restrict__ dti,
            const float* __restrict__ ddf,
            float* __restrict__ out)
{
    const int t = blockIdx.x * 256 + threadIdx.x;   // NVOX threads
#pragma unroll
    for (int b = 0; b < 2; ++b) {
        const int r = t;
        float* ob = out + (size_t)b * 6 * NVOX;
        const float v = ob[r];
        if (!(v != v)) continue;    // not NaN -> done

        const int x = r >> 12, y = (r >> 6) & 63, z = r & 63;
        const float* db = ddf + (size_t)b * 3 * NVOX;

        // warp (fp32 — M is well-conditioned)
        const float cx = fminf(fmaxf((float)x + db[r], 0.0f), 63.0f);
        const float cy = fminf(fmaxf((float)y + db[NVOX + r], 0.0f), 63.0f);
        const float cz = fminf(fmaxf((float)z + db[2 * NVOX + r], 0.0f), 63.0f);
        const float fx0 = floorf(cx), fy0 = floorf(cy), fz0 = floorf(cz);
        const float fx = cx - fx0, fy = cy - fy0, fz = cz - fz0;
        const int x0 = (int)fx0, y0 = (int)fy0, z0 = (int)fz0;
        const int x1 = min(x0 + 1, 63), y1 = min(y0 + 1, 63), z1 = min(z0 + 1, 63);
        const float gx = 1.0f - fx, gy = 1.0f - fy, gz = 1.0f - fz;
        const float w000 = gx*gy*gz, w001 = gx*gy*fz, w010 = gx*fy*gz, w011 = gx*fy*fz;
        const float w100 = fx*gy*gz, w101 = fx*gy*fz, w110 = fx*fy*gz, w111 = fx*fy*fz;
        const int o000 = (x0*64+y0)*64+z0, o001 = (x0*64+y0)*64+z1;
        const int o010 = (x0*64+y1)*64+z0, o011 = (x0*64+y1)*64+z1;
        const int o100 = (x1*64+y0)*64+z0, o101 = (x1*64+y0)*64+z1;
        const int o110 = (x1*64+y1)*64+z0, o111 = (x1*64+y1)*64+z1;

        const float* tb = dti + (size_t)b * 6 * NVOX;
        float m[6];
        for (int c = 0; c < 6; ++c) {
            const float* tc = tb + c * NVOX;
            m[c] = w000*tc[o000] + w001*tc[o001] + w010*tc[o010] + w011*tc[o011]
                 + w100*tc[o100] + w101*tc[o101] + w110*tc[o110] + w111*tc[o111];
        }

        // Jacobian fp64
        const int xm = max(x-1,0), xp = min(x+1,63);
        const int ym = max(y-1,0), yp = min(y+1,63);
        const int zm = max(z-1,0), zp = min(z+1,63);
        const double sx = (xp-xm==2)?0.5:1.0, sy = (yp-ym==2)?0.5:1.0, sz = (zp-zm==2)?0.5:1.0;
        double X[3][3];
        for (int i = 0; i < 3; ++i) {
            const float* ui = db + i * NVOX;
            X[i][0] = ((double)ui[(xp*64+y)*64+z] - (double)ui[(xm*64+y)*64+z]) * sx + (i==0?1.0:0.0);
            X[i][1] = ((double)ui[(x*64+yp)*64+z] - (double)ui[(x*64+ym)*64+z]) * sy + (i==1?1.0:0.0);
            X[i][2] = ((double)ui[(x*64+y)*64+zp] - (double)ui[(x*64+y)*64+zm]) * sz + (i==2?1.0:0.0);
        }

        // 14-iter normalized scaled-Newton polar (overflow-proof)
        for (int it = 0; it < 14; ++it) {
            double mx = 0.0;
            for (int i = 0; i < 3; ++i)
                for (int j = 0; j < 3; ++j) mx = fmax(mx, fabs(X[i][j]));
            const double s = 1.0 / fmax(mx, 1e-300);
            for (int i = 0; i < 3; ++i)
                for (int j = 0; j < 3; ++j) X[i][j] *= s;

            const double C00 = X[1][1]*X[2][2] - X[1][2]*X[2][1];
            const double C01 = X[1][2]*X[2][0] - X[1][0]*X[2][2];
            const double C02 = X[1][0]*X[2][1] - X[1][1]*X[2][0];
            const double C10 = X[0][2]*X[2][1] - X[0][1]*X[2][2];
            const double C11 = X[0][0]*X[2][2] - X[0][2]*X[2][0];
            const double C12 = X[0][1]*X[2][0] - X[0][0]*X[2][1];
            const double C20 = X[0][1]*X[1][2] - X[0][2]*X[1][1];
            const double C21 = X[0][2]*X[1][0] - X[0][0]*X[1][2];
            const double C22 = X[0][0]*X[1][1] - X[0][1]*X[1][0];
            const double det = X[0][0]*C00 + X[0][1]*C01 + X[0][2]*C02;
            const double n2 = X[0][0]*X[0][0]+X[0][1]*X[0][1]+X[0][2]*X[0][2]
                            + X[1][0]*X[1][0]+X[1][1]*X[1][1]+X[1][2]*X[1][2]
                            + X[2][0]*X[2][0]+X[2][1]*X[2][1]+X[2][2]*X[2][2];
            const double a2 = C00*C00+C01*C01+C02*C02 + C10*C10+C11*C11+C12*C12
                            + C20*C20+C21*C21+C22*C22;
            const double t2 = fmax(sqrt(a2 / n2), 1e-150);
            const double ad = fmax(fabs(det), 1e-280);
            const double sg = (det < 0.0) ? -1.0 : 1.0;
            const double c1 = 0.5 * sqrt(t2 / ad);
            const double c2 = 0.5 * sg / sqrt(t2 * ad);
            X[0][0]=c1*X[0][0]+c2*C00; X[0][1]=c1*X[0][1]+c2*C01; X[0][2]=c1*X[0][2]+c2*C02;
            X[1][0]=c1*X[1][0]+c2*C10; X[1][1]=c1*X[1][1]+c2*C11; X[1][2]=c1*X[1][2]+c2*C12;
            X[2][0]=c1*X[2][0]+c2*C20; X[2][1]=c1*X[2][1]+c2*C21; X[2][2]=c1*X[2][2]+c2*C22;
        }

        const double M3[3][3] = {{(double)m[0], (double)m[1], (double)m[3]},
                                 {(double)m[1], (double)m[2], (double)m[4]},
                                 {(double)m[3], (double)m[4], (double)m[5]}};
        double T[3][3], A[3][3];
        for (int i = 0; i < 3; ++i)
            for (int j = 0; j < 3; ++j)
                T[i][j] = X[0][i]*M3[0][j] + X[1][i]*M3[1][j] + X[2][i]*M3[2][j];
        for (int i = 0; i < 3; ++i)
            for (int j = 0; j < 3; ++j)
                A[i][j] = T[i][0]*X[0][j] + T[i][1]*X[1][j] + T[i][2]*X[2][j];

        ob[0 * NVOX + r] = (float)A[0][0];
        ob[1 * NVOX + r] = (float)A[1][0];
        ob[2 * NVOX + r] = (float)A[1][1];
        ob[3 * NVOX + r] = (float)A[2][0];
        ob[4 * NVOX + r] = (float)A[2][1];
        ob[5 * NVOX + r] = (float)A[2][2];
    }
}

extern "C" void kernel_launch(void* const* d_in, const int* in_sizes, int n_in,
                              void* d_out, int out_size, void* d_ws, size_t ws_size,
                              hipStream_t stream) {
    const float* dti = (const float*)d_in[0];
    const float* ddf = (const float*)d_in[1];
    float* out = (float*)d_out;
    warp_main<<<NVOX / 256, 256, 0, stream>>>(dti, ddf, out);   // 2 voxels/thread
    rescue<<<NVOX / 256, 256, 0, stream>>>(dti, ddf, out);
}

// Round 8
// 108.700 us; speedup vs baseline: 1.0842x; 1.0842x over previous
//
#include <hip/hip_runtime.h>

// Problem: B=2, C=6 (DTI lower-tri), H=W=D=64. fp32 in, fp32 out.
// out[b,c,x,y,z] = (R^T M R)[I[c],J[c]]
//   M = 3x3 symmetric from trilinear-warped DTI (border clamp, align_corners)
//   R = orthogonal polar factor of J = I + du/dx  (== U @ Vh of SVD(J))
// Pipeline: memset(bad=0) -> warp_main (fp32, 1 voxel/thread, list bad voxels)
//           -> rescue (fp64 re-solve of listed voxels).
// R6->R8: __launch_bounds__(256,8) for occupancy (latency-bound kernel),
// division-free 5-iter polar (rsqrtf), zero_count kernel -> hipMemsetAsync.
#define NVOX 262144          // 64^3
#define TOTAL (2 * NVOX)     // B * H * W * D threads

typedef float f2u __attribute__((ext_vector_type(2), aligned(4)));

__global__ __launch_bounds__(256, 8)   // force VGPR <= 64: 8 waves/SIMD
void warp_main(const float* __restrict__ dti,
               const float* __restrict__ ddf,
               float* __restrict__ out,
               int* __restrict__ bad, int max_bad)
{
    const int idx = blockIdx.x * 256 + threadIdx.x;   // exactly TOTAL threads
    const int b = idx >> 18;
    const int r = idx & (NVOX - 1);
    const int x = r >> 12;
    const int y = (r >> 6) & 63;
    const int z = r & 63;              // == lane

    const float* db = ddf + (size_t)b * 3 * NVOX;

    // ---------------- displacement at center ----------------
    const float ux = db[r];
    const float uy = db[NVOX + r];
    const float uz = db[2 * NVOX + r];

    // ---------------- trilinear warp, border padding ----------------
    const float cx = fminf(fmaxf((float)x + ux, 0.0f), 63.0f);
    const float cy = fminf(fmaxf((float)y + uy, 0.0f), 63.0f);
    const float cz = fminf(fmaxf((float)z + uz, 0.0f), 63.0f);
    const float fx0 = floorf(cx), fy0 = floorf(cy), fz0 = floorf(cz);
    const float fx = cx - fx0, fy = cy - fy0, fz = cz - fz0;
    const int x0 = (int)fx0, y0 = (int)fy0, z0 = (int)fz0;
    const int x1 = min(x0 + 1, 63), y1 = min(y0 + 1, 63);

    const float gx = 1.0f - fx, gy = 1.0f - fy, gz = 1.0f - fz;
    const float q00 = gx * gy, q01 = gx * fy, q10 = fx * gy, q11 = fx * fy;

    // z0/z1 adjacent -> one 8B load per (x,y) corner per channel (24 loads).
    // z0==63 only when cz==63 (fz=0): shift base to 62, take .y for z0.
    const bool ztop = (z0 == 63);
    const int zb = ztop ? 62 : z0;
    const int p00 = (x0 * 64 + y0) * 64 + zb, p01 = (x0 * 64 + y1) * 64 + zb;
    const int p10 = (x1 * 64 + y0) * 64 + zb, p11 = (x1 * 64 + y1) * 64 + zb;

    const float* tb = dti + (size_t)b * 6 * NVOX;
    float m[6];
#pragma unroll
    for (int c = 0; c < 6; ++c) {
        const float* tc = tb + c * NVOX;
        const f2u v00 = *(const f2u*)(tc + p00);
        const f2u v01 = *(const f2u*)(tc + p01);
        const f2u v10 = *(const f2u*)(tc + p10);
        const f2u v11 = *(const f2u*)(tc + p11);
        const float l00 = (ztop ? v00.y : v00.x) * gz + v00.y * fz;
        const float l01 = (ztop ? v01.y : v01.x) * gz + v01.y * fz;
        const float l10 = (ztop ? v10.y : v10.x) * gz + v10.y * fz;
        const float l11 = (ztop ? v11.y : v11.x) * gz + v11.y * fz;
        m[c] = q00 * l00 + q01 * l01 + q10 * l10 + q11 * l11;
    }

    // -------- Jacobian J = I + du/dx (np.gradient semantics), fp32 ---------
    const int xm = max(x - 1, 0), xp = min(x + 1, 63);
    const int ym = max(y - 1, 0), yp = min(y + 1, 63);
    const int zm = max(z - 1, 0), zp = min(z + 1, 63);
    const float sx = (xp - xm == 2) ? 0.5f : 1.0f;
    const float sy = (yp - ym == 2) ? 0.5f : 1.0f;
    const float sz = (zp - zm == 2) ? 0.5f : 1.0f;

    float P[3][3];
#pragma unroll
    for (int i = 0; i < 3; ++i) {
        const float* ui = db + i * NVOX;
        const float ctr = (i == 0) ? ux : (i == 1) ? uy : uz;
        P[i][0] = (ui[(xp * 64 + y) * 64 + z] - ui[(xm * 64 + y) * 64 + z]) * sx
                + (i == 0 ? 1.0f : 0.0f);
        P[i][1] = (ui[(x * 64 + yp) * 64 + z] - ui[(x * 64 + ym) * 64 + z]) * sy
                + (i == 1 ? 1.0f : 0.0f);
        // z-row lives in this wave: lane == z
        P[i][2] = (__shfl(ctr, zp) - __shfl(ctr, zm)) * sz + (i == 2 ? 1.0f : 0.0f);
    }

    // -------- fp32 scaled-Newton polar, 5 iters, division-free --------------
    // P <- c1*P + c2*cof(P); t = ||cof||/||P||, it2 = rsqrt(t*|d|),
    // c1 = 0.5*t*it2 (== 0.5*sqrt(t/|d|)), c2 = 0.5*sgn(d)*it2.
    bool ill = false;
#pragma unroll
    for (int it = 0; it < 5; ++it) {
        const float C00 = P[1][1] * P[2][2] - P[1][2] * P[2][1];
        const float C01 = P[1][2] * P[2][0] - P[1][0] * P[2][2];
        const float C02 = P[1][0] * P[2][1] - P[1][1] * P[2][0];
        const float C10 = P[0][2] * P[2][1] - P[0][1] * P[2][2];
        const float C11 = P[0][0] * P[2][2] - P[0][2] * P[2][0];
        const float C12 = P[0][1] * P[2][0] - P[0][0] * P[2][1];
        const float C20 = P[0][1] * P[1][2] - P[0][2] * P[1][1];
        const float C21 = P[0][2] * P[1][0] - P[0][0] * P[1][2];
        const float C22 = P[0][0] * P[1][1] - P[0][1] * P[1][0];
        const float det = P[0][0] * C00 + P[0][1] * C01 + P[0][2] * C02;

        const float n2 = P[0][0]*P[0][0] + P[0][1]*P[0][1] + P[0][2]*P[0][2]
                       + P[1][0]*P[1][0] + P[1][1]*P[1][1] + P[1][2]*P[1][2]
                       + P[2][0]*P[2][0] + P[2][1]*P[2][1] + P[2][2]*P[2][2];
        const float a2 = C00*C00 + C01*C01 + C02*C02
                       + C10*C10 + C11*C11 + C12*C12
                       + C20*C20 + C21*C21 + C22*C22;

        const float ad = fmaxf(fabsf(det), 1e-30f);
        if (it == 0) ill = (n2 * a2 > 1e8f * ad * ad);   // cond_F > 1e4

        const float t   = fmaxf(sqrtf(a2) * rsqrtf(n2), 1e-20f);
        const float it2 = rsqrtf(t * ad);
        const float sg  = (det < 0.0f) ? -0.5f : 0.5f;
        const float c1  = 0.5f * t * it2;
        const float c2  = sg * it2;

        P[0][0] = c1 * P[0][0] + c2 * C00;  P[0][1] = c1 * P[0][1] + c2 * C01;  P[0][2] = c1 * P[0][2] + c2 * C02;
        P[1][0] = c1 * P[1][0] + c2 * C10;  P[1][1] = c1 * P[1][1] + c2 * C11;  P[1][2] = c1 * P[1][2] + c2 * C12;
        P[2][0] = c1 * P[2][0] + c2 * C20;  P[2][1] = c1 * P[2][1] + c2 * C21;  P[2][2] = c1 * P[2][2] + c2 * C22;
    }

    // ---------------- A = R^T * M * R (lower-tri only) ----------------
    const float M3[3][3] = {{m[0], m[1], m[3]},
                            {m[1], m[2], m[4]},
                            {m[3], m[4], m[5]}};
    float T[3][3];
#pragma unroll
    for (int i = 0; i < 3; ++i)
#pragma unroll
        for (int j = 0; j < 3; ++j)
            T[i][j] = P[0][i] * M3[0][j] + P[1][i] * M3[1][j] + P[2][i] * M3[2][j];

    float* ob = out + (size_t)b * 6 * NVOX;
    ob[0 * NVOX + r] = T[0][0]*P[0][0] + T[0][1]*P[1][0] + T[0][2]*P[2][0];
    ob[1 * NVOX + r] = T[1][0]*P[0][0] + T[1][1]*P[1][0] + T[1][2]*P[2][0];
    ob[2 * NVOX + r] = T[1][0]*P[0][1] + T[1][1]*P[1][1] + T[1][2]*P[2][1];
    ob[3 * NVOX + r] = T[2][0]*P[0][0] + T[2][1]*P[1][0] + T[2][2]*P[2][0];
    ob[4 * NVOX + r] = T[2][0]*P[0][1] + T[2][1]*P[1][1] + T[2][2]*P[2][1];
    ob[5 * NVOX + r] = T[2][0]*P[0][2] + T[2][1]*P[1][2] + T[2][2]*P[2][2];

    // ---------------- flag ill-conditioned voxels for fp64 rescue -----------
    if (ill) {
        const int slot = atomicAdd(bad, 1);
        if (slot < max_bad) bad[1 + slot] = idx;
    }
}

// fp64 re-solve for the ~1e-4 fraction of voxels with near-singular J.
__global__ __launch_bounds__(256)
void rescue(const float* __restrict__ dti,
            const float* __restrict__ ddf,
            float* __restrict__ out,
            const int* __restrict__ bad, int max_bad)
{
    const int n = min(bad[0], max_bad);
    for (int k = blockIdx.x * 256 + threadIdx.x; k < n; k += 4 * 256) {
        const int idx = bad[1 + k];
        const int b = idx >> 18;
        const int r = idx & (NVOX - 1);
        const int x = r >> 12;
        const int y = (r >> 6) & 63;
        const int z = r & 63;

        const float* db = ddf + (size_t)b * 3 * NVOX;

        // warp (fp32 — M is well-conditioned)
        const float cx = fminf(fmaxf((float)x + db[r], 0.0f), 63.0f);
        const float cy = fminf(fmaxf((float)y + db[NVOX + r], 0.0f), 63.0f);
        const float cz = fminf(fmaxf((float)z + db[2 * NVOX + r], 0.0f), 63.0f);
        const float fx0 = floorf(cx), fy0 = floorf(cy), fz0 = floorf(cz);
        const float fx = cx - fx0, fy = cy - fy0, fz = cz - fz0;
        const int x0 = (int)fx0, y0 = (int)fy0, z0 = (int)fz0;
        const int x1 = min(x0 + 1, 63), y1 = min(y0 + 1, 63), z1 = min(z0 + 1, 63);
        const float gx = 1.0f - fx, gy = 1.0f - fy, gz = 1.0f - fz;
        const float w000 = gx*gy*gz, w001 = gx*gy*fz, w010 = gx*fy*gz, w011 = gx*fy*fz;
        const float w100 = fx*gy*gz, w101 = fx*gy*fz, w110 = fx*fy*gz, w111 = fx*fy*fz;
        const int o000 = (x0*64+y0)*64+z0, o001 = (x0*64+y0)*64+z1;
        const int o010 = (x0*64+y1)*64+z0, o011 = (x0*64+y1)*64+z1;
        const int o100 = (x1*64+y0)*64+z0, o101 = (x1*64+y0)*64+z1;
        const int o110 = (x1*64+y1)*64+z0, o111 = (x1*64+y1)*64+z1;

        const float* tb = dti + (size_t)b * 6 * NVOX;
        float m[6];
        for (int c = 0; c < 6; ++c) {
            const float* tc = tb + c * NVOX;
            m[c] = w000*tc[o000] + w001*tc[o001] + w010*tc[o010] + w011*tc[o011]
                 + w100*tc[o100] + w101*tc[o101] + w110*tc[o110] + w111*tc[o111];
        }

        // Jacobian fp64
        const int xm = max(x-1,0), xp = min(x+1,63);
        const int ym = max(y-1,0), yp = min(y+1,63);
        const int zm = max(z-1,0), zp = min(z+1,63);
        const double sx = (xp-xm==2)?0.5:1.0, sy = (yp-ym==2)?0.5:1.0, sz = (zp-zm==2)?0.5:1.0;
        double X[3][3];
        for (int i = 0; i < 3; ++i) {
            const float* ui = db + i * NVOX;
            X[i][0] = ((double)ui[(xp*64+y)*64+z] - (double)ui[(xm*64+y)*64+z]) * sx + (i==0?1.0:0.0);
            X[i][1] = ((double)ui[(x*64+yp)*64+z] - (double)ui[(x*64+ym)*64+z]) * sy + (i==1?1.0:0.0);
            X[i][2] = ((double)ui[(x*64+y)*64+zp] - (double)ui[(x*64+y)*64+zm]) * sz + (i==2?1.0:0.0);
        }

        // 14-iter normalized scaled-Newton polar (overflow-proof)
        for (int it = 0; it < 14; ++it) {
            double mx = 0.0;
            for (int i = 0; i < 3; ++i)
                for (int j = 0; j < 3; ++j) mx = fmax(mx, fabs(X[i][j]));
            const double s = 1.0 / fmax(mx, 1e-300);
            for (int i = 0; i < 3; ++i)
                for (int j = 0; j < 3; ++j) X[i][j] *= s;

            const double C00 = X[1][1]*X[2][2] - X[1][2]*X[2][1];
            const double C01 = X[1][2]*X[2][0] - X[1][0]*X[2][2];
            const double C02 = X[1][0]*X[2][1] - X[1][1]*X[2][0];
            const double C10 = X[0][2]*X[2][1] - X[0][1]*X[2][2];
            const double C11 = X[0][0]*X[2][2] - X[0][2]*X[2][0];
            const double C12 = X[0][1]*X[2][0] - X[0][0]*X[2][1];
            const double C20 = X[0][1]*X[1][2] - X[0][2]*X[1][1];
            const double C21 = X[0][2]*X[1][0] - X[0][0]*X[1][2];
            const double C22 = X[0][0]*X[1][1] - X[0][1]*X[1][0];
            const double det = X[0][0]*C00 + X[0][1]*C01 + X[0][2]*C02;
            const double n2 = X[0][0]*X[0][0]+X[0][1]*X[0][1]+X[0][2]*X[0][2]
                            + X[1][0]*X[1][0]+X[1][1]*X[1][1]+X[1][2]*X[1][2]
                            + X[2][0]*X[2][0]+X[2][1]*X[2][1]+X[2][2]*X[2][2];
            const double a2 = C00*C00+C01*C01+C02*C02 + C10*C10+C11*C11+C12*C12
                            + C20*C20+C21*C21+C22*C22;
            const double t2 = fmax(sqrt(a2 / n2), 1e-150);
            const double ad = fmax(fabs(det), 1e-280);
            const double sg = (det < 0.0) ? -1.0 : 1.0;
            const double c1 = 0.5 * sqrt(t2 / ad);
            const double c2 = 0.5 * sg / sqrt(t2 * ad);
            X[0][0]=c1*X[0][0]+c2*C00; X[0][1]=c1*X[0][1]+c2*C01; X[0][2]=c1*X[0][2]+c2*C02;
            X[1][0]=c1*X[1][0]+c2*C10; X[1][1]=c1*X[1][1]+c2*C11; X[1][2]=c1*X[1][2]+c2*C12;
            X[2][0]=c1*X[2][0]+c2*C20; X[2][1]=c1*X[2][1]+c2*C21; X[2][2]=c1*X[2][2]+c2*C22;
        }

        const double M3[3][3] = {{(double)m[0], (double)m[1], (double)m[3]},
                                 {(double)m[1], (double)m[2], (double)m[4]},
                                 {(double)m[3], (double)m[4], (double)m[5]}};
        double T[3][3], A[3][3];
        for (int i = 0; i < 3; ++i)
            for (int j = 0; j < 3; ++j)
                T[i][j] = X[0][i]*M3[0][j] + X[1][i]*M3[1][j] + X[2][i]*M3[2][j];
        for (int i = 0; i < 3; ++i)
            for (int j = 0; j < 3; ++j)
                A[i][j] = T[i][0]*X[0][j] + T[i][1]*X[1][j] + T[i][2]*X[2][j];

        float* ob = out + (size_t)b * 6 * NVOX;
        ob[0 * NVOX + r] = (float)A[0][0];
        ob[1 * NVOX + r] = (float)A[1][0];
        ob[2 * NVOX + r] = (float)A[1][1];
        ob[3 * NVOX + r] = (float)A[2][0];
        ob[4 * NVOX + r] = (float)A[2][1];
        ob[5 * NVOX + r] = (float)A[2][2];
    }
}

extern "C" void kernel_launch(void* const* d_in, const int* in_sizes, int n_in,
                              void* d_out, int out_size, void* d_ws, size_t ws_size,
                              hipStream_t stream) {
    const float* dti = (const float*)d_in[0];
    const float* ddf = (const float*)d_in[1];
    float* out = (float*)d_out;
    int* bad = (int*)d_ws;
    const int max_bad = (int)min((size_t)8192, ws_size / 4 - 1);

    hipMemsetAsync(bad, 0, sizeof(int), stream);   // graph-capture-legal
    warp_main<<<TOTAL / 256, 256, 0, stream>>>(dti, ddf, out, bad, max_bad);
    rescue<<<4, 256, 0, stream>>>(dti, ddf, out, bad, max_bad);
}